// Round 6
// baseline (106.456 us; speedup 1.0000x reference)
//
#include <hip/hip_runtime.h>
#include <math.h>

typedef unsigned short u16;
typedef unsigned int u32;
typedef __attribute__((ext_vector_type(4))) float f32x4;
typedef __attribute__((ext_vector_type(8))) short bf16x8;

#define NP 16
#define DLAT 768
#define HDIM 3072
#define NB 256
#define MAXO 250
#define TOT 2800

__device__ __forceinline__ u16 f2b(float f) {
  union { float f; u32 u; } v; v.f = f;
  u32 u = v.u;
  u32 r = (u + 0x7fffu + ((u >> 16) & 1u)) >> 16;
  return (u16)r;
}

__device__ __forceinline__ u32 cvtpk(float lo, float hi) {
  u32 r;
  asm("v_cvt_pk_bf16_f32 %0, %1, %2" : "=v"(r) : "v"(lo), "v"(hi));
  return r;
}

__device__ __forceinline__ void gll16(const void* g, void* l) {
  __builtin_amdgcn_global_load_lds(
      (const __attribute__((address_space(1))) void*)g,
      (__attribute__((address_space(3))) void*)l, 16, 0, 0);
}

// ---------------- LayerNorm: x[B,P,D] fp32 -> xn[P,B,D] bf16 ----------------
__global__ __launch_bounds__(256) void ln_kernel(
    const float* __restrict__ x, const float* __restrict__ gamma,
    const float* __restrict__ beta, u16* __restrict__ xn) {
  const int wave = threadIdx.x >> 6, lane = threadIdx.x & 63;
  const int row = blockIdx.x * 4 + wave;         // 0..4095 = b*16+p
  const int b = row >> 4, p = row & 15;
  const float4* xr = (const float4*)(x + (size_t)row * DLAT);
  const float4* g4 = (const float4*)(gamma + (size_t)p * DLAT);
  const float4* b4 = (const float4*)(beta + (size_t)p * DLAT);
  float4 v[3];
  float s = 0.f, ss = 0.f;
#pragma unroll
  for (int j = 0; j < 3; ++j) {
    v[j] = xr[lane + j * 64];
    s += v[j].x + v[j].y + v[j].z + v[j].w;
    ss += v[j].x * v[j].x + v[j].y * v[j].y + v[j].z * v[j].z + v[j].w * v[j].w;
  }
#pragma unroll
  for (int o = 32; o; o >>= 1) { s += __shfl_xor(s, o); ss += __shfl_xor(ss, o); }
  const float mu = s * (1.f / 768.f);
  const float var = ss * (1.f / 768.f) - mu * mu;
  const float rstd = rsqrtf(var + 1e-5f);
  u16* xo = xn + ((size_t)(p * NB + b)) * DLAT;
#pragma unroll
  for (int j = 0; j < 3; ++j) {
    const int f = lane + j * 64;
    float4 g = g4[f], be = b4[f];
    float o0 = (v[j].x - mu) * rstd * g.x + be.x;
    float o1 = (v[j].y - mu) * rstd * g.y + be.y;
    float o2 = (v[j].z - mu) * rstd * g.z + be.z;
    float o3 = (v[j].w - mu) * rstd * g.w + be.w;
    uint2 w;
    w.x = (u32)f2b(o0) | ((u32)f2b(o1) << 16);
    w.y = (u32)f2b(o2) | ((u32)f2b(o3) << 16);
    *(uint2*)&xo[f * 4] = w;
  }
}

// ---------------- fc1: h = GELU(xn @ w1^T)  per part ----------------
// m97 step structure (gll -> ds_read -> MFMA -> one __syncthreads), tile
// BM=128 x BN=64 x BK=32 so grid = 1536 (6/CU grid-side, 5/CU resident).
// BOTH A (bf16) and B (w1 fp32, kept fp32 in LDS) staged via global_load_lds
// with pre-swizzled global sources; B converted to bf16 in-register after the
// fragment ds_read (8 cvt_pk/step). 4 waves 2x2, each 64x32 (acc[4][2],
// 8 MFMA/step). Swizzles give <=2-way LDS access (free).
__global__ __launch_bounds__(256, 5) void fc1_kernel(
    const u16* __restrict__ xn, const float* __restrict__ w1, u16* __restrict__ h) {
  const int bid = blockIdx.x;            // 1536 blocks
  const int xcd = bid & 7;
  const int q = bid >> 3;                // 0..191 within XCD
  const int g = xcd * 96 + (q >> 1);     // (p,n0) group 0..767; 2 M-siblings adjacent
  const int mb = q & 1;
  const int p = g / 48;
  const int n0 = (g % 48) * 64;
  const int m0 = mb * 128;

  const int tid = threadIdx.x;
  const int lane = tid & 63, wave = tid >> 6;
  const int lanelo = lane & 15, lanehi = lane >> 4;
  const int wr = wave >> 1, wc = wave & 1;

  const u16* Ap = xn + (size_t)p * NB * DLAT + (size_t)m0 * DLAT;
  const float* Bp = w1 + (size_t)p * HDIM * DLAT + (size_t)n0 * DLAT;

  __shared__ u16 AsU[2][128 * 32];     // 8 KiB each: [row][4 chunks x 16B] bf16
  __shared__ float BsF[2][64 * 32];    // 8 KiB each: [row][8 chunks x 16B] fp32

  // A gll: 2 chunks/thread; physical slot s holds global k-chunk (s&3)^((r>>1)&3)
  int a_src[2], a_dst[2];
#pragma unroll
  for (int i = 0; i < 2; ++i) {
    const int s = wave * 128 + i * 64 + lane;
    const int r = s >> 2;
    const int gg = (s & 3) ^ ((r >> 1) & 3);
    a_src[i] = r * DLAT + gg * 8;          // u16 elems
    a_dst[i] = (wave * 128 + i * 64) * 8;  // wave-uniform base (u16 elems)
  }
  // B gll: 2 chunks/thread; physical slot s holds global k-chunk (s&7)^(r&7)
  int b_src[2], b_dst[2];
#pragma unroll
  for (int i = 0; i < 2; ++i) {
    const int s = wave * 128 + i * 64 + lane;
    const int r = s >> 3;
    const int gg = (s & 7) ^ (r & 7);
    b_src[i] = r * DLAT + gg * 4;          // floats
    b_dst[i] = (wave * 128 + i * 64) * 4;  // wave-uniform base (floats)
  }
  // fragment read offsets (kt-independent)
  int a_sl[4];
#pragma unroll
  for (int m = 0; m < 4; ++m) {
    const int ra = wr * 64 + m * 16 + lanelo;
    a_sl[m] = (ra * 4 + (lanehi ^ ((ra >> 1) & 3))) * 8;   // u16 elems
  }
  int b_sl[2][2];
#pragma unroll
  for (int n = 0; n < 2; ++n) {
    const int rbl = wc * 32 + n * 16 + lanelo;
#pragma unroll
    for (int jj = 0; jj < 2; ++jj)
      b_sl[n][jj] = rbl * 32 + ((2 * lanehi + jj) ^ (rbl & 7)) * 4;  // floats
  }

  f32x4 acc[4][2] = {};
  const int NK = DLAT / 32;  // 24

  auto stage = [&](int kt) {
    const int k2 = kt * 32;
#pragma unroll
    for (int i = 0; i < 2; ++i)
      gll16(Ap + a_src[i] + k2, &AsU[kt & 1][a_dst[i]]);
#pragma unroll
    for (int i = 0; i < 2; ++i)
      gll16(Bp + b_src[i] + k2, &BsF[kt & 1][b_dst[i]]);
  };

  stage(0);
  __syncthreads();
#pragma unroll 2
  for (int kt = 0; kt < NK; ++kt) {
    const int cur = kt & 1;
    if (kt + 1 < NK) stage(kt + 1);
    const u16* a_ = &AsU[cur][0];
    const float* b_ = &BsF[cur][0];
    bf16x8 af[4], bf[2];
#pragma unroll
    for (int m = 0; m < 4; ++m) af[m] = *(const bf16x8*)&a_[a_sl[m]];
#pragma unroll
    for (int n = 0; n < 2; ++n) {
      const float4 f0 = *(const float4*)&b_[b_sl[n][0]];
      const float4 f1 = *(const float4*)&b_[b_sl[n][1]];
      union { u32 u[4]; bf16x8 v; } t;
      t.u[0] = cvtpk(f0.x, f0.y); t.u[1] = cvtpk(f0.z, f0.w);
      t.u[2] = cvtpk(f1.x, f1.y); t.u[3] = cvtpk(f1.z, f1.w);
      bf[n] = t.v;
    }
#pragma unroll
    for (int m = 0; m < 4; ++m)
#pragma unroll
      for (int n = 0; n < 2; ++n)
        acc[m][n] = __builtin_amdgcn_mfma_f32_16x16x32_bf16(af[m], bf[n], acc[m][n], 0, 0, 0);
    __syncthreads();
  }

  // epilogue: exact GELU, store bf16
  u16* hp = h + (size_t)p * NB * HDIM;
#pragma unroll
  for (int m = 0; m < 4; ++m) {
#pragma unroll
    for (int n = 0; n < 2; ++n) {
      const int col = n0 + wc * 32 + n * 16 + lanelo;
#pragma unroll
      for (int r = 0; r < 4; ++r) {
        const int row = m0 + wr * 64 + m * 16 + lanehi * 4 + r;
        const float vv = acc[m][n][r];
        const float gel = 0.5f * vv * (1.f + erff(vv * 0.70710678118654752f));
        hp[(size_t)row * HDIM + col] = f2b(gel);
      }
    }
  }
}

// ---------------- fc2: out = h @ w2^T + b2, concat slices ----------------
// BM=64, BN=64, BK=32; 4 waves 2x2, each 32x32. (validated, ~memory floor)
__global__ __launch_bounds__(256) void fc2_kernel(
    const u16* __restrict__ hbuf, const float* __restrict__ w2,
    const float* __restrict__ b2, float* __restrict__ out) {
  const int bid = blockIdx.x;
  const int bs = (bid & 7) * 32 + (bid >> 3);    // XCD swizzle (256 = 8*32)
  const int p = bs >> 4;
  const int mb = (bs >> 2) & 3;
  const int nb = bs & 3;
  const int odim = 100 + 10 * p;
  const int n0 = nb * 64;
  if (n0 >= odim) return;                        // uniform per block
  const int m0 = mb * 64;
  const int off = 100 * p + 5 * p * (p - 1);

  const int tid = threadIdx.x;
  const int lane = tid & 63, wave = tid >> 6;
  const int lanelo = lane & 15, lanehi = lane >> 4;
  const int wr = wave >> 1, wc = wave & 1;

  const u16* Ap = hbuf + (size_t)p * NB * HDIM + (size_t)m0 * HDIM;
  const float* Bp = w2 + (size_t)p * MAXO * HDIM;

  __shared__ u16 As[3][64 * 32];   // 12 KiB
  __shared__ u16 Bs[2][64 * 32];   // 8 KiB

  int ag_off;
  const int ag_base = (64 * wave) * 8;
  {
    int slot = 64 * wave + lane;
    int r = slot >> 2;
    int c = (slot & 3) ^ ((r >> 1) & 3);
    ag_off = r * HDIM + c * 8;
  }
  const int br0 = min(n0 + (tid >> 3), MAXO - 1);
  const int br1 = min(n0 + (tid >> 3) + 32, MAXO - 1);
  const float* bg0 = Bp + (size_t)br0 * HDIM + (tid & 7) * 4;
  const float* bg1 = Bp + (size_t)br1 * HDIM + (tid & 7) * 4;
  int bso[2];
#pragma unroll
  for (int i = 0; i < 2; ++i) {
    int r = (tid >> 3) + 32 * i;
    int c = ((tid & 7) >> 1) ^ ((r >> 1) & 3);
    bso[i] = (r * 4 + c) * 8 + (tid & 1) * 4;
  }
  int a_sl[2], b_sl[2];
#pragma unroll
  for (int m = 0; m < 2; ++m) {
    int r = wr * 32 + m * 16 + lanelo;
    a_sl[m] = (r * 4 + (lanehi ^ ((r >> 1) & 3))) * 8;
    int rb = wc * 32 + m * 16 + lanelo;
    b_sl[m] = (rb * 4 + (lanehi ^ ((rb >> 1) & 3))) * 8;
  }

  f32x4 acc[2][2] = {};
  float4 bA0, bA1, bB0, bB1;
  const int NK = HDIM / 32;  // 96

  auto issue = [&](int kt, float4& r0, float4& r1) {
    const int k2 = kt * 32;
    gll16(Ap + ag_off + k2, &As[kt % 3][ag_base]);
    asm volatile("" ::: "memory");
    r0 = *(const float4*)(bg0 + k2);
    r1 = *(const float4*)(bg1 + k2);
    asm volatile("" ::: "memory");
  };

  auto step = [&](int kt, float4& r0, float4& r1) {
    if (kt + 1 < NK) asm volatile("s_waitcnt vmcnt(3)" ::: "memory");
    else             asm volatile("s_waitcnt vmcnt(0)" ::: "memory");
    {
      u16* bb = &Bs[kt & 1][0];
      uint2 w0, w1v;
      w0.x = (u32)f2b(r0.x) | ((u32)f2b(r0.y) << 16);
      w0.y = (u32)f2b(r0.z) | ((u32)f2b(r0.w) << 16);
      w1v.x = (u32)f2b(r1.x) | ((u32)f2b(r1.y) << 16);
      w1v.y = (u32)f2b(r1.z) | ((u32)f2b(r1.w) << 16);
      *(uint2*)&bb[bso[0]] = w0;
      *(uint2*)&bb[bso[1]] = w1v;
    }
    asm volatile("s_waitcnt lgkmcnt(0)" ::: "memory");
    __builtin_amdgcn_s_barrier();
    asm volatile("" ::: "memory");
    if (kt + 2 < NK) issue(kt + 2, r0, r1);
    const u16* a_ = &As[kt % 3][0];
    const u16* b_ = &Bs[kt & 1][0];
    bf16x8 af[2], bf[2];
#pragma unroll
    for (int m = 0; m < 2; ++m) af[m] = *(const bf16x8*)&a_[a_sl[m]];
#pragma unroll
    for (int n = 0; n < 2; ++n) bf[n] = *(const bf16x8*)&b_[b_sl[n]];
#pragma unroll
    for (int m = 0; m < 2; ++m)
#pragma unroll
      for (int n = 0; n < 2; ++n)
        acc[m][n] = __builtin_amdgcn_mfma_f32_16x16x32_bf16(af[m], bf[n], acc[m][n], 0, 0, 0);
  };

  issue(0, bA0, bA1);
  issue(1, bB0, bB1);
  for (int kt = 0; kt < NK; kt += 2) {
    step(kt, bA0, bA1);
    step(kt + 1, bB0, bB1);
  }

#pragma unroll
  for (int m = 0; m < 2; ++m) {
#pragma unroll
    for (int n = 0; n < 2; ++n) {
      const int col = n0 + wc * 32 + n * 16 + lanelo;
      if (col < odim) {
        const float bias = b2[(size_t)p * MAXO + col];
#pragma unroll
        for (int r = 0; r < 4; ++r) {
          const int row = m0 + wr * 32 + m * 16 + lanehi * 4 + r;
          out[(size_t)row * TOT + off + col] = acc[m][n][r] + bias;
        }
      }
    }
  }
}

extern "C" void kernel_launch(void* const* d_in, const int* in_sizes, int n_in,
                              void* d_out, int out_size, void* d_ws, size_t ws_size,
                              hipStream_t stream) {
  const float* x = (const float*)d_in[0];
  const float* gamma = (const float*)d_in[1];
  const float* beta = (const float*)d_in[2];
  const float* w1 = (const float*)d_in[3];
  const float* w2 = (const float*)d_in[4];
  const float* b2 = (const float*)d_in[5];
  float* out = (float*)d_out;

  u16* xn = (u16*)d_ws;                             // [16][256][768] bf16
  u16* h = (u16*)d_ws + (size_t)NP * NB * DLAT;     // [16][256][3072] bf16

  ln_kernel<<<1024, 256, 0, stream>>>(x, gamma, beta, xn);
  fc1_kernel<<<1536, 256, 0, stream>>>(xn, w1, h);
  fc2_kernel<<<NP * 16, 256, 0, stream>>>(h, w2, b2, out);
}